// Round 10
// baseline (242.116 us; speedup 1.0000x reference)
//
#include <hip/hip_runtime.h>
#include <stdint.h>

constexpr int kN = 16384;
constexpr int kD = 256;
constexpr int TM = 256, TN = 256;   // block tile 256x256
constexpr int KB = kD / 2;          // fp4 row = 128 bytes

using floatx16 = __attribute__((ext_vector_type(16))) float;  // 32x32 MFMA C/D
using floatx2  = __attribute__((ext_vector_type(2))) float;   // v_pk_* pair
using intx2v   = __attribute__((ext_vector_type(2))) int;
using intx4    = __attribute__((ext_vector_type(4))) int;
using intx8    = __attribute__((ext_vector_type(8))) int;     // f8f6f4 operand

// fp32*16 -> fp4 e2m1 RNE. Codes 0..7 = {0,.5,1,1.5,2,3,4,6} ARE the bit
// patterns (monotone). Thresholds are the RNE midpoints. (R12-verified.)
__device__ __forceinline__ uint32_t q4(float x) {
    float y = fabsf(x * 16.f);
    uint32_t c = (y >= 0.25f) + (y >= 0.75f) + (y >= 1.25f) + (y >= 1.75f)
               + (y >= 2.5f)  + (y >= 3.5f)  + (y >= 5.0f);
    return c | (x < 0.f ? 8u : 0u);
}

// A row-major; B CHUNK-MAJOR B'[c][row] (c = 16B K-chunk). R23: B's
// transposed store now goes through a tiny LDS regroup -- R21's direct
// scatter put 32 lanes on 64KB-strided lines (16x store inefficiency).
// LDS [8][36] dwords: write banks (4row+4c+w)%32 unique per 32-lane group,
// read banks (4r+w) unique -- both conflict-free. Stores become 128B runs.
__global__ __launch_bounds__(256)
void cvt_fp4_kernel(const float* __restrict__ a, const float* __restrict__ b,
                    unsigned int* __restrict__ oa, unsigned int* __restrict__ ob,
                    float* __restrict__ out) {
    __shared__ uint32_t lb[8][36];
    const int t = threadIdx.x;
    const int idx = blockIdx.x * 256 + t;
    if (idx == 0) *out = 0.f;
    float4 a0 = *(const float4*)(a + (size_t)idx * 8);
    float4 a1 = *(const float4*)(a + (size_t)idx * 8 + 4);
    float4 b0 = *(const float4*)(b + (size_t)idx * 8);
    float4 b1 = *(const float4*)(b + (size_t)idx * 8 + 4);
    uint32_t pa = q4(a0.x) | (q4(a0.y) << 4) | (q4(a0.z) << 8)  | (q4(a0.w) << 12)
                | (q4(a1.x) << 16) | (q4(a1.y) << 20) | (q4(a1.z) << 24) | (q4(a1.w) << 28);
    uint32_t pb = q4(b0.x) | (q4(b0.y) << 4) | (q4(b0.z) << 8)  | (q4(b0.w) << 12)
                | (q4(b1.x) << 16) | (q4(b1.y) << 20) | (q4(b1.z) << 24) | (q4(b1.w) << 28);
    oa[idx] = pa;
    // block covers rows b*8..b*8+7, all 8 chunks x 4 dwords
    const int row = t >> 5, d = t & 31;
    lb[row][(d >> 2) * 4 + (d & 3)] = pb;
    __syncthreads();
    const int c2 = t >> 5, r2 = (t >> 2) & 7, w2 = t & 3;
    ob[((size_t)c2 * kN + blockIdx.x * 8 + r2) * 4 + w2] = lb[r2][c2 * 4 + w2];
}

// Undef-high 8-reg tuple from one 4-reg quad: fp4 MFMA reads only v[0:3]
// (HW-validated R14/R15/R19/R20/R21/R22: absmax 0.0).
#define U8(v)  __builtin_shufflevector((v), (v), 0, 1, 2, 3, -1, -1, -1, -1)
#define MFMA4(a, b, c) __builtin_amdgcn_mfma_scale_f32_32x32x64_f8f6f4( \
        (a), (b), (c), 4 /*cbsz fp4*/, 4 /*blgp fp4*/, 0, 127, 0, 127)

// async global->LDS, 16B per lane. LDS dst = wave-uniform base + lane*16.
__device__ __forceinline__ void gl2lds16(const unsigned char* g, unsigned char* l) {
    __builtin_amdgcn_global_load_lds(
        (const __attribute__((address_space(1))) unsigned int*)g,
        (__attribute__((address_space(3))) unsigned int*)l, 16, 0, 0);
}

// R23: 8-chain diagonal schedule. R22 falsified compiler-de-interleave (SGB
// = zero effect). Re-derivation: MFMA pipe busy ~= floor (13us); the stall
// is per-wave ISSUE, and the one structure whose chains were latency-hidden
// was R13's acc[4][2] -- 8 independent chains, same-acc spacing 8 MFMAs with
// ~30 VALU between (its cost was mov-bloat + raw-global B, both since
// fixed). Every later round narrowed to 1-4 chains / tight spacing and
// pinned at 27% MfmaUtil. This round: R13 chain geometry + R21 LDS B +
// mov-free U8 + packed epi, scheduled DIAGONALLY per tile:
//   group g: [4 epiQ of prev-tile block g] m(g,q0) m(g-1,q1) m(g-2,q2) m(g-3,q3)
// Same-block q->q+1 gap = one group (~90-140cy) ~= dep latency -> hidden;
// epi VALU is the spacing material; epi(block g) sits right before block
// g's q0 overwrite (WAR by adjacency). Registers = R13-proven shape
// (VGPR 72 + 128 acc AGPR, no spill) + bl[2][4] 32.
// Pre-commit: gates pass but MfmaUtil<=33% => 2 waves/SIMD can't feed the
// scaled-fp4 pipe; R24 pivots to 4 waves/SIMD.
__global__ __launch_bounds__(512, 2)
void siglip_gemm_loss_kernel(const unsigned char* __restrict__ A,   // fp4 [N][KB]
                             const unsigned char* __restrict__ Bc,  // fp4 chunk-major
                             const float* __restrict__ scale_p,
                             const float* __restrict__ bias_p,
                             float* __restrict__ out) {
    __shared__ unsigned char ldsB[8][2][8192];   // [wave][buf][chunk-major 8x64x16B]
    __shared__ float red[8];

    const int tid  = threadIdx.x;
    const int wave = tid >> 6;     // 0..7
    const int lane = tid & 63;

    const int g    = blockIdx.x;                  // 256 persistent blocks
    const int tRow = ((g & 7) << 3) + (g >> 5);   // fixed tile-row (A-stripe L2-hot)
    const int sCol = (g >> 3) & 3;                // tile s -> col sCol + 4s

    const int wr = wave >> 2, wc = wave & 3;   // 2x4 waves
    const int m0 = wr * 128, n0 = wc * 64;     // wave tile 128x64
    const int l31 = lane & 31;
    const int h   = lane >> 5;                 // K-half: byte offset 16h

    const float sc  = *scale_p * (1.0f / 256.0f);   // undo x16 x16 prescale
    const float bs  = *bias_p;
    const float sc3 = sc * (1.44269504f * 8388608.0f);
    const float bs3 = fmaf(bs, 1.44269504f * 8388608.0f, 1064986823.0f);
    const floatx2 sc3v = (floatx2)(sc3);
    const floatx2 bs3v = (floatx2)(bs3);

    // ---- A operand: loop-invariant, resident as raw intx4 quads (row-major A).
    intx4 af[4][4];
    #pragma unroll
    for (int i = 0; i < 4; ++i) {
        const unsigned char* pa = A + ((size_t)tRow * TM + m0 + i * 32 + l31) * KB + 16 * h;
        #pragma unroll
        for (int q = 0; q < 4; ++q)
            af[i][q] = *(const intx4*)(pa + q * 32);
    }

    const floatx16 z16 = (floatx16)(0.f);   // C operand of each block's q0 MFMA

    floatx16 acc[4][2];             // 8 independent accumulator chains (128 AGPR)
    floatx2 sm0 = (floatx2)(0.f), sm1 = (floatx2)(0.f);
    float smd = 0.f;                // diagonal correction accumulator

    // ---- staging: chunk i (16B of K) for the wave's 64 B-rows (R21-proven).
    const unsigned char* pSrcLane =
        Bc + ((size_t)(sCol * TN + n0) + lane) * 16;
    auto stageT = [&](const int s) {
        const unsigned char* src = pSrcLane + (size_t)s * (4 * TN * 16);
        unsigned char* dst = &ldsB[wave][s & 1][0];
        #pragma unroll
        for (int i = 0; i < 8; ++i)
            gl2lds16(src + (size_t)i * (kN * 16), dst + i * 1024);
    };

    // ---- B tile read: quad (j,q) = chunk c=2q+h, row j*32+l31 (conflict-free).
    intx4 bl[2][4];
    auto ldsLoadT = [&](const int s) {
        const unsigned char* base = &ldsB[wave][s & 1][h * 1024 + l31 * 16];
        #pragma unroll
        for (int j = 0; j < 2; ++j)
            #pragma unroll
            for (int q = 0; q < 4; ++q)
                bl[j][q] = *(const intx4*)(base + q * 2048 + j * 512);
    };

    // one MFMA of block bk (i=bk&3, j=bk>>2), K-quad q; q0 starts from z16.
    auto mstep = [&](const int bk, const int q) {
        const int i = bk & 3, j = bk >> 2;
        acc[i][j] = MFMA4(U8(af[i][q]), U8(bl[j][q]),
                          q == 0 ? z16 : acc[i][j]);
    };

    // one epi slice: 4 elems starting at vb (2 pk_fma + 4 cvt + 2 pk_add)
    auto epiQ = [&](const floatx16& ae, const int vb) {
        floatx2 t0 = {ae[vb + 0], ae[vb + 1]};
        floatx2 t1 = {ae[vb + 2], ae[vb + 3]};
        t0 = __builtin_elementwise_fma(t0, sc3v, bs3v);  // v_pk_fma_f32
        t1 = __builtin_elementwise_fma(t1, sc3v, bs3v);
        const intx2v e0 = {(int)t0.x, (int)t0.y};        // v_cvt_i32_f32
        const intx2v e1 = {(int)t1.x, (int)t1.y};
        sm0 += __builtin_bit_cast(floatx2, e0);          // v_pk_add_f32
        sm1 += __builtin_bit_cast(floatx2, e1);
    };

    // full epilogue of block bk for tile-col tColE (reads acc BEFORE q0
    // overwrite -- placed immediately before mstep(bk,0) in program order).
    auto epiB = [&](const int bk, const int tColE) {
        const int i = bk & 3, j = bk >> 2;
        epiQ(acc[i][j], 0); epiQ(acc[i][j], 4);
        epiQ(acc[i][j], 8); epiQ(acc[i][j], 12);
        const int gRow0 = tRow * TM + m0 + i * 32;
        const int gCol0 = tColE * TN + n0 + j * 32;
        if (gRow0 == gCol0) {   // wave-uniform, rare
            #pragma unroll
            for (int v = 0; v < 16; ++v) {
                const int rrow = (v & 3) + 8 * (v >> 2) + 4 * h;
                if (rrow == l31) smd += fmaf(acc[i][j][v], sc, bs);
            }
        }
    };

    // ---- main loop: barrier-free vmcnt-counted staging + diagonal schedule.
    stageT(0);
    // s = 0 peeled (no previous-tile epilogue)
    stageT(1);
    asm volatile("s_waitcnt vmcnt(8)" ::: "memory");
    ldsLoadT(0);
    #pragma unroll
    for (int gp = 0; gp < 11; ++gp) {
        if (gp < 8)             mstep(gp, 0);
        if (gp >= 1 && gp < 9)  mstep(gp - 1, 1);
        if (gp >= 2 && gp < 10) mstep(gp - 2, 2);
        if (gp >= 3)            mstep(gp - 3, 3);
    }
    for (int s = 1; s < 16; ++s) {
        if (s < 15) {
            stageT(s + 1);                                   // 8 more in flight
            asm volatile("s_waitcnt vmcnt(8)" ::: "memory"); // stage(s) landed
        } else {
            asm volatile("s_waitcnt vmcnt(0)" ::: "memory");
        }
        ldsLoadT(s);
        const int cP = sCol + 4 * (s - 1);
        #pragma unroll
        for (int gp = 0; gp < 11; ++gp) {
            if (gp < 8)             { epiB(gp, cP); mstep(gp, 0); }
            if (gp >= 1 && gp < 9)  mstep(gp - 1, 1);
            if (gp >= 2 && gp < 10) mstep(gp - 2, 2);
            if (gp >= 3)            mstep(gp - 3, 3);
        }
    }
    // drain tile 15's epilogues
    {
        const int cL = sCol + 60;
        #pragma unroll
        for (int bk = 0; bk < 8; ++bk) epiB(bk, cL);
    }

    float sum = (sm0.x + sm1.x) + (sm0.y + sm1.y) - smd;

    // block reduce -> ONE atomicAdd per block (256 total, spread in time)
    #pragma unroll
    for (int off = 32; off > 0; off >>= 1)
        sum += __shfl_down(sum, off);
    if (lane == 0) red[wave] = sum;
    __syncthreads();
    if (tid == 0) {
        float s2 = 0.f;
        #pragma unroll
        for (int w = 0; w < 8; ++w) s2 += red[w];
        atomicAdd(out, s2 * (1.0f / (float)kN));
    }
}

extern "C" void kernel_launch(void* const* d_in, const int* in_sizes, int n_in,
                              void* d_out, int out_size, void* d_ws, size_t ws_size,
                              hipStream_t stream) {
    const float* img     = (const float*)d_in[0];
    const float* txt     = (const float*)d_in[1];
    const float* scale_p = (const float*)d_in[2];
    const float* bias_p  = (const float*)d_in[3];
    float* out = (float*)d_out;

    unsigned char* Af4 = (unsigned char*)d_ws;            // N*KB = 2 MiB (row-major)
    unsigned char* Bf4 = Af4 + (size_t)kN * KB;           // 2 MiB (chunk-major)

    cvt_fp4_kernel<<<dim3(kN * kD / 8 / 256), dim3(256), 0, stream>>>(
        img, txt, (unsigned int*)Af4, (unsigned int*)Bf4, out);
    siglip_gemm_loss_kernel<<<dim3(256), dim3(512), 0, stream>>>(
        Af4, Bf4, scale_p, bias_p, out);
}

// Round 11
// 120.062 us; speedup vs baseline: 2.0166x; 2.0166x over previous
//
#include <hip/hip_runtime.h>
#include <stdint.h>

constexpr int kN = 16384;
constexpr int kD = 256;
constexpr int TM = 256, TN = 256;   // block tile 256x256
constexpr int KB = kD / 2;          // fp4 row = 128 bytes

using floatx16 = __attribute__((ext_vector_type(16))) float;  // 32x32 MFMA C/D
using floatx2  = __attribute__((ext_vector_type(2))) float;   // v_pk_* pair
using intx2v   = __attribute__((ext_vector_type(2))) int;
using intx4    = __attribute__((ext_vector_type(4))) int;
using intx8    = __attribute__((ext_vector_type(8))) int;     // f8f6f4 operand

// fp32*16 -> fp4 e2m1 RNE. Codes 0..7 = {0,.5,1,1.5,2,3,4,6} ARE the bit
// patterns (monotone). Thresholds are the RNE midpoints. (R12-verified.)
__device__ __forceinline__ uint32_t q4(float x) {
    float y = fabsf(x * 16.f);
    uint32_t c = (y >= 0.25f) + (y >= 0.75f) + (y >= 1.25f) + (y >= 1.75f)
               + (y >= 2.5f)  + (y >= 3.5f)  + (y >= 5.0f);
    return c | (x < 0.f ? 8u : 0u);
}

// A row-major; B CHUNK-MAJOR B'[c][row] (c = 16B K-chunk) via small LDS
// regroup -> coalesced 128B store runs (R23 cvt, refcheck'd absmax 0.0).
__global__ __launch_bounds__(256)
void cvt_fp4_kernel(const float* __restrict__ a, const float* __restrict__ b,
                    unsigned int* __restrict__ oa, unsigned int* __restrict__ ob,
                    float* __restrict__ out) {
    __shared__ uint32_t lb[8][36];
    const int t = threadIdx.x;
    const int idx = blockIdx.x * 256 + t;
    if (idx == 0) *out = 0.f;
    float4 a0 = *(const float4*)(a + (size_t)idx * 8);
    float4 a1 = *(const float4*)(a + (size_t)idx * 8 + 4);
    float4 b0 = *(const float4*)(b + (size_t)idx * 8);
    float4 b1 = *(const float4*)(b + (size_t)idx * 8 + 4);
    uint32_t pa = q4(a0.x) | (q4(a0.y) << 4) | (q4(a0.z) << 8)  | (q4(a0.w) << 12)
                | (q4(a1.x) << 16) | (q4(a1.y) << 20) | (q4(a1.z) << 24) | (q4(a1.w) << 28);
    uint32_t pb = q4(b0.x) | (q4(b0.y) << 4) | (q4(b0.z) << 8)  | (q4(b0.w) << 12)
                | (q4(b1.x) << 16) | (q4(b1.y) << 20) | (q4(b1.z) << 24) | (q4(b1.w) << 28);
    oa[idx] = pa;
    const int row = t >> 5, d = t & 31;
    lb[row][(d >> 2) * 4 + (d & 3)] = pb;
    __syncthreads();
    const int c2 = t >> 5, r2 = (t >> 2) & 7, w2 = t & 3;
    ob[((size_t)c2 * kN + blockIdx.x * 8 + r2) * 4 + w2] = lb[r2][c2 * 4 + w2];
}

// Undef-high 8-reg tuple from one 4-reg quad: fp4 MFMA reads only v[0:3]
// (HW-validated R14-R23: absmax 0.0).
#define U8(v)  __builtin_shufflevector((v), (v), 0, 1, 2, 3, -1, -1, -1, -1)
#define MFMA4(a, b, c) __builtin_amdgcn_mfma_scale_f32_32x32x64_f8f6f4( \
        (a), (b), (c), 4 /*cbsz fp4*/, 4 /*blgp fp4*/, 0, 127, 0, 127)

// async global->LDS, 16B per lane. LDS dst = wave-uniform base + lane*16.
__device__ __forceinline__ void gl2lds16(const unsigned char* g, unsigned char* l) {
    __builtin_amdgcn_global_load_lds(
        (const __attribute__((address_space(1))) unsigned int*)g,
        (__attribute__((address_space(3))) unsigned int*)l, 16, 0, 0);
}

// R24: restore SPACING-8 MFMA issue (the R13 geometry), keep every later
// hygiene win. Key diagnosis: MfmaUtil pinned at 25-29% across R15/R20/R21/
// R22 = 35cy pipe-occupancy / ~140cy dep latency -- every one of those
// structures issued MFMAs in dependent chains of 4 with spacing <=2, so the
// matrix pipe ran at DEP-LATENCY rate. R13 (q-outer, 8 independent chains,
// same-acc spacing 8 ~= 280cy >> 140cy) was pipe-rate; its cost was scalar
// epi + mov bloat + raw-global B -- each fixed since, never together with
// the chain-8 M-phase. This round: R13 M-phase (for q: for i: for j) +
// R21 LDS-staged conflict-free chunk-major B + U8 mov-free operands +
// packed epilogue, phase-separated (M then E per tile -- the shape the
// allocator provably handles: acc[4][2] stays in 128 AGPRs, no z16, epi
// resets acc like R13). Per SIMD per tile: M = 2 waves x 32 x 35.4 = 2266cy
// pipe-saturated even lockstep; E ~730cy; -> ~21us GEMM, MfmaUtil ~70%.
// Pre-commit: gates pass but MfmaUtil<=33% => dep-spacing theory dead,
// R25 pivots dtype (fp8 non-scaled).
__global__ __launch_bounds__(512, 2)
void siglip_gemm_loss_kernel(const unsigned char* __restrict__ A,   // fp4 [N][KB]
                             const unsigned char* __restrict__ Bc,  // fp4 chunk-major
                             const float* __restrict__ scale_p,
                             const float* __restrict__ bias_p,
                             float* __restrict__ out) {
    __shared__ unsigned char ldsB[8][2][8192];   // [wave][buf][chunk-major 8x64x16B]
    __shared__ float red[8];

    const int tid  = threadIdx.x;
    const int wave = tid >> 6;     // 0..7
    const int lane = tid & 63;

    const int g    = blockIdx.x;                  // 256 persistent blocks
    const int tRow = ((g & 7) << 3) + (g >> 5);   // fixed tile-row (A-stripe L2-hot)
    const int sCol = (g >> 3) & 3;                // tile s -> col sCol + 4s

    const int wr = wave >> 2, wc = wave & 3;   // 2x4 waves
    const int m0 = wr * 128, n0 = wc * 64;     // wave tile 128x64
    const int l31 = lane & 31;
    const int h   = lane >> 5;                 // K-half: byte offset 16h

    const float sc  = *scale_p * (1.0f / 256.0f);   // undo x16 x16 prescale
    const float bs  = *bias_p;
    const float sc3 = sc * (1.44269504f * 8388608.0f);
    const float bs3 = fmaf(bs, 1.44269504f * 8388608.0f, 1064986823.0f);
    const floatx2 sc3v = (floatx2)(sc3);
    const floatx2 bs3v = (floatx2)(bs3);

    // ---- A operand: loop-invariant, resident as raw intx4 quads (row-major A).
    intx4 af[4][4];
    #pragma unroll
    for (int i = 0; i < 4; ++i) {
        const unsigned char* pa = A + ((size_t)tRow * TM + m0 + i * 32 + l31) * KB + 16 * h;
        #pragma unroll
        for (int q = 0; q < 4; ++q)
            af[i][q] = *(const intx4*)(pa + q * 32);
    }

    floatx16 acc[4][2];             // 8 independent chains, 128 AGPR (R13 shape)
    #pragma unroll
    for (int i = 0; i < 4; ++i)
        #pragma unroll
        for (int j = 0; j < 2; ++j) acc[i][j] = (floatx16)(0.f);
    floatx2 sm0 = (floatx2)(0.f), sm1 = (floatx2)(0.f);
    float smd = 0.f;                // diagonal correction accumulator

    // ---- staging: chunk i (16B of K) for the wave's 64 B-rows (R21-proven).
    const unsigned char* pSrcLane =
        Bc + ((size_t)(sCol * TN + n0) + lane) * 16;
    auto stageT = [&](const int s) {
        const unsigned char* src = pSrcLane + (size_t)s * (4 * TN * 16);
        unsigned char* dst = &ldsB[wave][s & 1][0];
        #pragma unroll
        for (int i = 0; i < 8; ++i)
            gl2lds16(src + (size_t)i * (kN * 16), dst + i * 1024);
    };

    // ---- B tile read: quad (j,q) = chunk c=2q+h, row j*32+l31 (conflict-free).
    intx4 bl[2][4];
    auto ldsLoadT = [&](const int s) {
        const unsigned char* base = &ldsB[wave][s & 1][h * 1024 + l31 * 16];
        #pragma unroll
        for (int j = 0; j < 2; ++j)
            #pragma unroll
            for (int q = 0; q < 4; ++q)
                bl[j][q] = *(const intx4*)(base + q * 2048 + j * 512);
    };

    // ---- M phase: 32 MFMAs, q-outer -> 8 independent MFMAs per q-round,
    // same-acc spacing 8 (~280cy at pipe rate) >> dep latency -> pipe-bound.
    auto mfmaT = [&]() {
        #pragma unroll
        for (int q = 0; q < 4; ++q)
            #pragma unroll
            for (int i = 0; i < 4; ++i)
                #pragma unroll
                for (int j = 0; j < 2; ++j)
                    acc[i][j] = MFMA4(U8(af[i][q]), U8(bl[j][q]), acc[i][j]);
    };

    // one epi slice: 4 elems starting at vb (2 pk_fma + 4 cvt + 2 pk_add)
    auto epiQ = [&](const floatx16& ae, const int vb) {
        floatx2 t0 = {ae[vb + 0], ae[vb + 1]};
        floatx2 t1 = {ae[vb + 2], ae[vb + 3]};
        t0 = __builtin_elementwise_fma(t0, sc3v, bs3v);  // v_pk_fma_f32
        t1 = __builtin_elementwise_fma(t1, sc3v, bs3v);
        const intx2v e0 = {(int)t0.x, (int)t0.y};        // v_cvt_i32_f32
        const intx2v e1 = {(int)t1.x, (int)t1.y};
        sm0 += __builtin_bit_cast(floatx2, e0);          // v_pk_add_f32
        sm1 += __builtin_bit_cast(floatx2, e1);
    };

    // ---- E phase: full-tile epilogue + acc reset (R13-proven shape).
    auto epiT = [&](const int tCol) {
        #pragma unroll
        for (int i = 0; i < 4; ++i)
            #pragma unroll
            for (int j = 0; j < 2; ++j) {
                epiQ(acc[i][j], 0); epiQ(acc[i][j], 4);
                epiQ(acc[i][j], 8); epiQ(acc[i][j], 12);
                const int gRow0 = tRow * TM + m0 + i * 32;
                const int gCol0 = tCol * TN + n0 + j * 32;
                if (gRow0 == gCol0) {   // wave-uniform, rare
                    #pragma unroll
                    for (int v = 0; v < 16; ++v) {
                        const int rrow = (v & 3) + 8 * (v >> 2) + 4 * h;
                        if (rrow == l31) smd += fmaf(acc[i][j][v], sc, bs);
                    }
                }
                acc[i][j] = (floatx16)(0.f);
            }
    };

    // ---- main loop: barrier-free vmcnt-counted staging, phase-separated M/E.
    stageT(0);
    for (int s = 0; s < 16; ++s) {
        if (s < 15) {
            stageT(s + 1);                                   // 8 more in flight
            asm volatile("s_waitcnt vmcnt(8)" ::: "memory"); // stage(s) landed
        } else {
            asm volatile("s_waitcnt vmcnt(0)" ::: "memory");
        }
        ldsLoadT(s);                // 8 ds_read_b128, conflict-free
        mfmaT();                    // M: pipe-rate issue
        epiT(sCol + 4 * s);         // E: packed epi + reset
    }

    float sum = (sm0.x + sm1.x) + (sm0.y + sm1.y) - smd;

    // block reduce -> ONE atomicAdd per block (256 total, spread in time)
    #pragma unroll
    for (int off = 32; off > 0; off >>= 1)
        sum += __shfl_down(sum, off);
    if (lane == 0) red[wave] = sum;
    __syncthreads();
    if (tid == 0) {
        float s2 = 0.f;
        #pragma unroll
        for (int w = 0; w < 8; ++w) s2 += red[w];
        atomicAdd(out, s2 * (1.0f / (float)kN));
    }
}

extern "C" void kernel_launch(void* const* d_in, const int* in_sizes, int n_in,
                              void* d_out, int out_size, void* d_ws, size_t ws_size,
                              hipStream_t stream) {
    const float* img     = (const float*)d_in[0];
    const float* txt     = (const float*)d_in[1];
    const float* scale_p = (const float*)d_in[2];
    const float* bias_p  = (const float*)d_in[3];
    float* out = (float*)d_out;

    unsigned char* Af4 = (unsigned char*)d_ws;            // N*KB = 2 MiB (row-major)
    unsigned char* Bf4 = Af4 + (size_t)kN * KB;           // 2 MiB (chunk-major)

    cvt_fp4_kernel<<<dim3(kN * kD / 8 / 256), dim3(256), 0, stream>>>(
        img, txt, (unsigned int*)Af4, (unsigned int*)Bf4, out);
    siglip_gemm_loss_kernel<<<dim3(256), dim3(512), 0, stream>>>(
        Af4, Bf4, scale_p, bias_p, out);
}